// Round 14
// baseline (865.454 us; speedup 1.0000x reference)
//
#include <hip/hip_runtime.h>
#include <hip/hip_bf16.h>

typedef unsigned int   u32;
typedef unsigned short u16;
typedef _Float16       f16;
typedef __attribute__((ext_vector_type(2))) _Float16 f16x2;
typedef __attribute__((ext_vector_type(8))) _Float16 f16x8;
typedef __attribute__((ext_vector_type(4))) float    f32x4;
typedef __attribute__((ext_vector_type(4))) u32      u32x4;

#define T_STEPS 512
#define BATCH   256
#define O_IN    720
#define KPAD    736      // 720 padded to mult of 32 (zero pad in wxt)
#define HID     128
#define G4      512      // 4*HID
// d_out layout (floats): am[512] | std[2] | value[256] | hT[32768] | cT[32768]
#define OUT_STD 512
#define OUT_VAL 514
#define OUT_HT  770
#define OUT_CT  33538

// ws layout (bytes); requires ws_size >= ~135 MB
static const unsigned long long XW_OFF  = 0ull;          // f16 [131072][512] = 134217728 B
static const unsigned long long WXT_OFF = 134217728ull;  // f16 [512][736]    = 753664 B

// raw transcendental asm: v_exp_f32 computes 2^x (1 trans op); v_rcp_f32 ~1ulp (R11-validated).
__device__ inline float exp2raw(float x){
  float r; asm("v_exp_f32 %0, %1" : "=v"(r) : "v"(x)); return r;
}
__device__ inline float rcpraw(float x){
  float r; asm("v_rcp_f32 %0, %1" : "=v"(r) : "v"(x)); return r;
}
__device__ inline float tanhfast(float x){
  return fmaf(2.f, rcpraw(1.0f + exp2raw(-2.88539008f * x)), -1.f);
}

// d = a.lo*b.lo + a.hi*b.hi + c  (f16 pairs, f32 accum) — inline asm (builtin broken:
// R2/R8 bit-identical failures; asm validated R9-R11, absmax 0.0078).
__device__ inline float dot2f(u32 a, u32 b, float c){
  float d;
  asm("v_dot2_f32_f16 %0, %1, %2, %3" : "=v"(d) : "v"(a), "v"(b), "v"(c));
  return d;
}

// h stored as f16 in LDS, SINGLE buffer (R14: two barriers/step remove all
// double-buffer rotation subtleties — R12/R13's differing-error signature says race).
#define HH_STRIDE 144
#define H_BYTES   (2*HH_STRIDE)
#define HW_OFF(j) (((j)>>6)*HH_STRIDE + ((j)&63)*2)

// ---------------- K0: Wx (720,512) f32 -> Wx^T f16 [512][736] zero-padded ----------------
__global__ void k_pack_wxt(const float* __restrict__ Wx, u16* __restrict__ wxt){
  const int n = blockIdx.x;               // 512 blocks
  for (int k = threadIdx.x; k < KPAD; k += 256){
    float v = (k < O_IN) ? Wx[(size_t)k * G4 + n] : 0.f;
    wxt[(size_t)n * KPAD + k] = __builtin_bit_cast(u16, (f16)v);
  }
}

// ---------------- K1: xW = x @ Wx  (fp16 MFMA, LDS-free, no barriers) --------------------
// Unchanged (validated; outputs pass through it).
__global__ __launch_bounds__(256, 2) void k_gemm(const float* __restrict__ x,
                                                 const u16* __restrict__ wxt,
                                                 u16* __restrict__ xw)
{
  const int l  = threadIdx.x & 63;
  const int w  = threadIdx.x >> 6;
  const int lr = l & 15;
  const int lk = l >> 4;
  const u32 L  = (blockIdx.x & 7u) * 256u + (blockIdx.x >> 3);
  const u32 mb = L >> 2, nb = L & 3u;
  const u32 M0 = mb * 256u + (u32)w * 64u;
  const u32 N0 = nb * 128u;

  const float* ax[4];
  const u16*   bx[8];
#pragma unroll
  for (int mf = 0; mf < 4; ++mf)
    ax[mf] = x + (unsigned long long)(M0 + mf*16 + lr) * O_IN + lk*8;
#pragma unroll
  for (int nf = 0; nf < 8; ++nf)
    bx[nf] = wxt + (unsigned long long)(N0 + nf*16 + lr) * KPAD + lk*8;

  f32x4 acc[4][8];
#pragma unroll
  for (int mf = 0; mf < 4; ++mf)
#pragma unroll
    for (int nf = 0; nf < 8; ++nf)
      acc[mf][nf] = (f32x4){0.f, 0.f, 0.f, 0.f};

  f32x4 a0[4][2];
  f16x8 aF[4], bF[8];

#pragma unroll
  for (int mf = 0; mf < 4; ++mf){
    a0[mf][0] = *(const f32x4*)(ax[mf]);
    a0[mf][1] = *(const f32x4*)(ax[mf] + 4);
  }
#pragma unroll
  for (int nf = 0; nf < 8; ++nf)
    bF[nf] = *(const f16x8*)(bx[nf]);
#pragma unroll
  for (int mf = 0; mf < 4; ++mf){
    f32x4 lo = a0[mf][0], hi = a0[mf][1];
    f16x8 v; v[0]=(f16)lo.x; v[1]=(f16)lo.y; v[2]=(f16)lo.z; v[3]=(f16)lo.w;
             v[4]=(f16)hi.x; v[5]=(f16)hi.y; v[6]=(f16)hi.z; v[7]=(f16)hi.w;
    aF[mf] = v;
  }

  for (int kc = 0; kc < 22; ++kc){
    if (kc < 21){
#pragma unroll
      for (int mf = 0; mf < 4; ++mf){
        a0[mf][0] = *(const f32x4*)(ax[mf] + (kc+1)*32);
        a0[mf][1] = *(const f32x4*)(ax[mf] + (kc+1)*32 + 4);
      }
    }
#pragma unroll
    for (int nf = 0; nf < 8; ++nf){
#pragma unroll
      for (int mf = 0; mf < 4; ++mf)
        acc[mf][nf] = __builtin_amdgcn_mfma_f32_16x16x32_f16(aF[mf], bF[nf], acc[mf][nf], 0, 0, 0);
      if (kc < 21)
        bF[nf] = *(const f16x8*)(bx[nf] + (kc+1)*32);
    }
    if (kc < 21){
#pragma unroll
      for (int mf = 0; mf < 4; ++mf){
        f32x4 lo = a0[mf][0], hi = a0[mf][1];
        f16x8 v; v[0]=(f16)lo.x; v[1]=(f16)lo.y; v[2]=(f16)lo.z; v[3]=(f16)lo.w;
                 v[4]=(f16)hi.x; v[5]=(f16)hi.y; v[6]=(f16)hi.z; v[7]=(f16)hi.w;
        aF[mf] = v;
      }
    }
  }

  {
    f16x8 aT[4];
#pragma unroll
    for (int mf = 0; mf < 4; ++mf) aT[mf] = (f16x8)(f16)0.f;
    if (lk < 2){
#pragma unroll
      for (int mf = 0; mf < 4; ++mf){
        f32x4 lo = *(const f32x4*)(ax[mf] + 704);
        f32x4 hi = *(const f32x4*)(ax[mf] + 708);
        f16x8 v; v[0]=(f16)lo.x; v[1]=(f16)lo.y; v[2]=(f16)lo.z; v[3]=(f16)lo.w;
                 v[4]=(f16)hi.x; v[5]=(f16)hi.y; v[6]=(f16)hi.z; v[7]=(f16)hi.w;
        aT[mf] = v;
      }
    }
#pragma unroll
    for (int nf = 0; nf < 8; ++nf){
      f16x8 bT = *(const f16x8*)(bx[nf] + 704);
#pragma unroll
      for (int mf = 0; mf < 4; ++mf)
        acc[mf][nf] = __builtin_amdgcn_mfma_f32_16x16x32_f16(aT[mf], bT, acc[mf][nf], 0, 0, 0);
    }
  }

#pragma unroll
  for (int mf = 0; mf < 4; ++mf){
    const u32 rowb = M0 + mf*16 + lk*4;
#pragma unroll
    for (int nf = 0; nf < 8; ++nf){
      const u32 col = N0 + nf*16 + lr;
#pragma unroll
      for (int r = 0; r < 4; ++r)
        xw[(unsigned long long)(rowb + r) * G4 + col] = __builtin_bit_cast(u16, (f16)acc[mf][nf][r]);
    }
  }
}

// ---------------- K2: LSTM scan v4 — 1024 thr, SINGLE buffer, TWO barriers/step -----------
// Decisive race experiment: v3 mapping (audited clean 3x) with all rotation/visibility
// subtleties removed. Cross-lane ONLY via __shfl_xor/__shfl (R5-R7-proven).
// PASS => R12/13 were a race. FAIL ~0.1 => revert scan to R11 next round.
__global__ __attribute__((amdgpu_flat_work_group_size(1024,1024), amdgpu_waves_per_eu(4,4)))
void k_rnn(
    const u16* __restrict__ xw, const float* __restrict__ Wh,
    const float* __restrict__ h0, const float* __restrict__ c0,
    const float* __restrict__ bvec,
    const float* __restrict__ Wa1, const float* __restrict__ ba1,
    const float* __restrict__ Wa2, const float* __restrict__ ba2,
    const float* __restrict__ Wc1, const float* __restrict__ bc1,
    const float* __restrict__ Wc2, const float* __restrict__ bc2,
    const float* __restrict__ log_std, float* __restrict__ out)
{
  const int b = blockIdx.x;
  const int t = threadIdx.x;          // 0..1023
  const int j = t >> 3;               // col 0..127
  const int g = (t >> 1) & 3;         // gate 0:i 1:f 2:g 3:o
  const int q = t & 1;                // k-half
  const int l = t & 63;               // lane
  const int lb = l & 56;              // 8-lane group base

  __shared__ __align__(16) char hbuf[H_BYTES];     // h f16, SINGLE buffer
  __shared__ __align__(16) float hf[HID];          // final h fp32 (heads)
  __shared__ float hid[256];

  // ---- weights: wg[m] = f16x2{ Wh[64q+2m][j+128g], Wh[64q+2m+1][j+128g] }, m=0..31 ----
  u32 wg[32];
#pragma unroll
  for (int m = 0; m < 32; ++m){
    const u32 kb = (u32)(64*q + 2*m) * G4 + (u32)(j + 128*g);
    f16x2 p; p[0] = (f16)Wh[kb]; p[1] = (f16)Wh[kb + G4];
    wg[m] = __builtin_bit_cast(u32, p);
  }
#pragma unroll
  for (int m = 0; m < 32; ++m) asm volatile("" : "+v"(wg[m]));   // pin (R7 lesson)

  const float bb = bvec[j + 128*g];
  // per-gate activation constants: g==2 -> tanh(x)=2*sig(2x)-1, else sigmoid
  const float kexp  = (g == 2) ? -2.88539008f : -1.44269504f;
  const float postm = (g == 2) ? 2.f : 1.f;
  const float posta = (g == 2) ? -1.f : 0.f;

  // ---- state (replicated across the 8 lanes of col j) ----
  float cs = c0[b*HID + j];
  float hv = h0[b*HID + j];
  if ((t & 7) == 0)
    *(u16*)(hbuf + HW_OFF(j)) = __builtin_bit_cast(u16, (f16)hv);
  __syncthreads();

  const u16* xp = xw + (u32)b * G4 + (u32)(j + 128*g);
  float xc  = (float)__builtin_bit_cast(f16, xp[0]) + bb;
  float xn1 = (T_STEPS > 1) ? (float)__builtin_bit_cast(f16, xp[131072u]) + bb : 0.f;

  for (int s = 0; s < T_STEPS; ++s){
    const char* hq = hbuf + q * HH_STRIDE;

    float xn2 = 0.f;
    if (s + 2 < T_STEPS)
      xn2 = (float)__builtin_bit_cast(f16, xp[(u32)(s+2) * 131072u]) + bb;

    float p0 = 0.f, p1 = 0.f, p2 = 0.f, p3 = 0.f;   // 4 chains of 8 dot2
#pragma unroll
    for (int it = 0; it < 8; ++it){
      u32x4 hh = *(const u32x4*)(hq + it*16);       // broadcast, bank-disjoint halves
      p0 = dot2f(hh.x, wg[4*it+0], p0);
      p1 = dot2f(hh.y, wg[4*it+1], p1);
      p2 = dot2f(hh.z, wg[4*it+2], p2);
      p3 = dot2f(hh.w, wg[4*it+3], p3);
    }
    float p = (p0 + p1) + (p2 + p3);
    p += __shfl_xor(p, 1);                           // + partner k-half (proven primitive)

    float gval = p + xc;                             // full gate pre-activation
    float av   = fmaf(postm, rcpraw(1.0f + exp2raw(kexp * gval)), posta);

    // gather the 4 gate activations of col j (proven __shfl broadcast pattern)
    float ai = __shfl(av, lb | 0);
    float af = __shfl(av, lb | 2);
    float ag = __shfl(av, lb | 4);
    float ao = __shfl(av, lb | 6);

    cs = af * cs + ai * ag;
    hv = ao * tanhfast(cs);

    __syncthreads();                 // ALL reads of hbuf for step s complete
    if ((t & 7) == 0)
      *(u16*)(hbuf + HW_OFF(j)) = __builtin_bit_cast(u16, (f16)hv);
    __syncthreads();                 // h[s+1] visible to all
    xc = xn1; xn1 = xn2;
  }

  if ((t & 7) == 0){                 // exact fp32 state out
    out[OUT_HT + b*HID + j] = hv;
    out[OUT_CT + b*HID + j] = cs;
    hf[j] = hv;
  }
  __syncthreads();

  if (t < 256){ // heads hidden, fp32: t<128 -> actor col t; else critic col t-128
    const float* W = (t < HID) ? Wa1 : Wc1;
    const int col  = t & (HID - 1);
    const f32x4* hp4 = (const f32x4*)hf;
    float a0 = 0.f, a1 = 0.f, a2 = 0.f, a3 = 0.f;
#pragma unroll
    for (int qq = 0; qq < 32; ++qq){
      f32x4 hh = hp4[qq];
      a0 = fmaf(hh.x, W[(u32)(4*qq+0)*HID + col], a0);
      a1 = fmaf(hh.y, W[(u32)(4*qq+1)*HID + col], a1);
      a2 = fmaf(hh.z, W[(u32)(4*qq+2)*HID + col], a2);
      a3 = fmaf(hh.w, W[(u32)(4*qq+3)*HID + col], a3);
    }
    float a = (a0 + a1) + (a2 + a3);
    hid[t] = (t < HID) ? tanhfast(a + ba1[col]) : tanhfast(a + bc1[col]);
  }
  __syncthreads();

  {
    const int wv = t >> 6, lane = t & 63;
    float p = 0.f;
    if (wv == 0)      p = hid[lane]     * Wa2[lane*2]   + hid[lane+64]     * Wa2[(lane+64)*2];
    else if (wv == 1) p = hid[lane]     * Wa2[lane*2+1] + hid[lane+64]     * Wa2[(lane+64)*2+1];
    else if (wv == 2) p = hid[128+lane] * Wc2[lane]     + hid[128+lane+64] * Wc2[lane+64];
    if (wv < 3){
#pragma unroll
      for (int off = 32; off > 0; off >>= 1) p += __shfl_down(p, off);
      if (lane == 0){
        if (wv == 0) out[b*2 + 0]   = p + ba2[0];
        if (wv == 1) out[b*2 + 1]   = p + ba2[1];
        if (wv == 2) out[OUT_VAL+b] = p + bc2[0];
      }
    }
    if (b == 0 && wv == 3 && lane < 2) out[OUT_STD + lane] = expf(log_std[lane]);
  }
}

extern "C" void kernel_launch(void* const* d_in, const int* in_sizes, int n_in,
                              void* d_out, int out_size, void* d_ws, size_t ws_size,
                              hipStream_t stream)
{
  (void)in_sizes; (void)n_in; (void)out_size; (void)ws_size;
  const float* x    = (const float*)d_in[0];
  const float* h0   = (const float*)d_in[1];
  const float* c0   = (const float*)d_in[2];
  const float* Wx   = (const float*)d_in[3];
  const float* Wh   = (const float*)d_in[4];
  const float* bv   = (const float*)d_in[5];
  const float* Wa1  = (const float*)d_in[6];
  const float* ba1  = (const float*)d_in[7];
  const float* Wa2  = (const float*)d_in[8];
  const float* ba2  = (const float*)d_in[9];
  const float* lstd = (const float*)d_in[10];
  const float* Wc1  = (const float*)d_in[11];
  const float* bc1  = (const float*)d_in[12];
  const float* Wc2  = (const float*)d_in[13];
  const float* bc2  = (const float*)d_in[14];
  float* out = (float*)d_out;
  char*  ws  = (char*)d_ws;

  u16* xw  = (u16*)(ws + XW_OFF);
  u16* wxt = (u16*)(ws + WXT_OFF);

  k_pack_wxt<<<dim3(512),  dim3(256),  0, stream>>>(Wx, wxt);
  k_gemm<<<dim3(2048),     dim3(256),  0, stream>>>(x, wxt, xw);
  k_rnn<<<dim3(256),       dim3(1024), 0, stream>>>(xw, Wh, h0, c0, bv,
                                                    Wa1, ba1, Wa2, ba2, Wc1, bc1, Wc2, bc2,
                                                    lstd, out);
}

// Round 15
// 815.409 us; speedup vs baseline: 1.0614x; 1.0614x over previous
//
#include <hip/hip_runtime.h>
#include <hip/hip_bf16.h>

typedef unsigned int   u32;
typedef unsigned short u16;
typedef _Float16       f16;
typedef __attribute__((ext_vector_type(2))) _Float16 f16x2;
typedef __attribute__((ext_vector_type(8))) _Float16 f16x8;
typedef __attribute__((ext_vector_type(4))) float    f32x4;
typedef __attribute__((ext_vector_type(4))) u32      u32x4;

#define T_STEPS 512
#define BATCH   256
#define O_IN    720
#define KPAD    736      // 720 padded to mult of 32 (zero pad in wxt)
#define HID     128
#define G4      512      // 4*HID
// d_out layout (floats): am[512] | std[2] | value[256] | hT[32768] | cT[32768]
#define OUT_STD 512
#define OUT_VAL 514
#define OUT_HT  770
#define OUT_CT  33538

// ws layout (bytes); requires ws_size >= ~135 MB
static const unsigned long long XW_OFF  = 0ull;          // f16 [131072][512] = 134217728 B
static const unsigned long long WXT_OFF = 134217728ull;  // f16 [512][736]    = 753664 B

// raw transcendental asm (R11-validated): v_exp_f32 = 2^x; v_rcp_f32 ~1ulp.
__device__ inline float exp2raw(float x){
  float r; asm("v_exp_f32 %0, %1" : "=v"(r) : "v"(x)); return r;
}
__device__ inline float rcpraw(float x){
  float r; asm("v_rcp_f32 %0, %1" : "=v"(r) : "v"(x)); return r;
}
__device__ inline float tanhfast(float x){
  return fmaf(2.f, rcpraw(1.0f + exp2raw(-2.88539008f * x)), -1.f);
}

// f16-pair dot2, inline asm (builtin broken: R2/R8; asm proven R9-R14).
__device__ inline float dot2f(u32 a, u32 b, float c){
  float d;
  asm("v_dot2_f32_f16 %0, %1, %2, %3" : "=v"(d) : "v"(a), "v"(b), "v"(c));
  return d;
}

// DPP quad_perm (VALU pipe; ctrls 177/78/0/85/170/255 all HW-proven in R11-pass).
#define DPPF(x, ctrl) \
  __uint_as_float((u32)__builtin_amdgcn_update_dpp(0, (int)__float_as_uint(x), (ctrl), 0xF, 0xF, false))

// ---------------- K0: Wx (720,512) f32 -> Wx^T f16 [512][736] zero-padded ----------------
__global__ void k_pack_wxt(const float* __restrict__ Wx, u16* __restrict__ wxt){
  const int n = blockIdx.x;               // 512 blocks
  for (int k = threadIdx.x; k < KPAD; k += 256){
    float v = (k < O_IN) ? Wx[(size_t)k * G4 + n] : 0.f;
    wxt[(size_t)n * KPAD + k] = __builtin_bit_cast(u16, (f16)v);
  }
}

// ---------------- K1: xW = x @ Wx  (fp16 MFMA, LDS-free, no barriers) --------------------
// Unchanged (validated; outputs pass through it).
__global__ __launch_bounds__(256, 2) void k_gemm(const float* __restrict__ x,
                                                 const u16* __restrict__ wxt,
                                                 u16* __restrict__ xw)
{
  const int l  = threadIdx.x & 63;
  const int w  = threadIdx.x >> 6;
  const int lr = l & 15;
  const int lk = l >> 4;
  const u32 L  = (blockIdx.x & 7u) * 256u + (blockIdx.x >> 3);
  const u32 mb = L >> 2, nb = L & 3u;
  const u32 M0 = mb * 256u + (u32)w * 64u;
  const u32 N0 = nb * 128u;

  const float* ax[4];
  const u16*   bx[8];
#pragma unroll
  for (int mf = 0; mf < 4; ++mf)
    ax[mf] = x + (unsigned long long)(M0 + mf*16 + lr) * O_IN + lk*8;
#pragma unroll
  for (int nf = 0; nf < 8; ++nf)
    bx[nf] = wxt + (unsigned long long)(N0 + nf*16 + lr) * KPAD + lk*8;

  f32x4 acc[4][8];
#pragma unroll
  for (int mf = 0; mf < 4; ++mf)
#pragma unroll
    for (int nf = 0; nf < 8; ++nf)
      acc[mf][nf] = (f32x4){0.f, 0.f, 0.f, 0.f};

  f32x4 a0[4][2];
  f16x8 aF[4], bF[8];

#pragma unroll
  for (int mf = 0; mf < 4; ++mf){
    a0[mf][0] = *(const f32x4*)(ax[mf]);
    a0[mf][1] = *(const f32x4*)(ax[mf] + 4);
  }
#pragma unroll
  for (int nf = 0; nf < 8; ++nf)
    bF[nf] = *(const f16x8*)(bx[nf]);
#pragma unroll
  for (int mf = 0; mf < 4; ++mf){
    f32x4 lo = a0[mf][0], hi = a0[mf][1];
    f16x8 v; v[0]=(f16)lo.x; v[1]=(f16)lo.y; v[2]=(f16)lo.z; v[3]=(f16)lo.w;
             v[4]=(f16)hi.x; v[5]=(f16)hi.y; v[6]=(f16)hi.z; v[7]=(f16)hi.w;
    aF[mf] = v;
  }

  for (int kc = 0; kc < 22; ++kc){
    if (kc < 21){
#pragma unroll
      for (int mf = 0; mf < 4; ++mf){
        a0[mf][0] = *(const f32x4*)(ax[mf] + (kc+1)*32);
        a0[mf][1] = *(const f32x4*)(ax[mf] + (kc+1)*32 + 4);
      }
    }
#pragma unroll
    for (int nf = 0; nf < 8; ++nf){
#pragma unroll
      for (int mf = 0; mf < 4; ++mf)
        acc[mf][nf] = __builtin_amdgcn_mfma_f32_16x16x32_f16(aF[mf], bF[nf], acc[mf][nf], 0, 0, 0);
      if (kc < 21)
        bF[nf] = *(const f16x8*)(bx[nf] + (kc+1)*32);
    }
    if (kc < 21){
#pragma unroll
      for (int mf = 0; mf < 4; ++mf){
        f32x4 lo = a0[mf][0], hi = a0[mf][1];
        f16x8 v; v[0]=(f16)lo.x; v[1]=(f16)lo.y; v[2]=(f16)lo.z; v[3]=(f16)lo.w;
                 v[4]=(f16)hi.x; v[5]=(f16)hi.y; v[6]=(f16)hi.z; v[7]=(f16)hi.w;
        aF[mf] = v;
      }
    }
  }

  {
    f16x8 aT[4];
#pragma unroll
    for (int mf = 0; mf < 4; ++mf) aT[mf] = (f16x8)(f16)0.f;
    if (lk < 2){
#pragma unroll
      for (int mf = 0; mf < 4; ++mf){
        f32x4 lo = *(const f32x4*)(ax[mf] + 704);
        f32x4 hi = *(const f32x4*)(ax[mf] + 708);
        f16x8 v; v[0]=(f16)lo.x; v[1]=(f16)lo.y; v[2]=(f16)lo.z; v[3]=(f16)lo.w;
                 v[4]=(f16)hi.x; v[5]=(f16)hi.y; v[6]=(f16)hi.z; v[7]=(f16)hi.w;
        aT[mf] = v;
      }
    }
#pragma unroll
    for (int nf = 0; nf < 8; ++nf){
      f16x8 bT = *(const f16x8*)(bx[nf] + 704);
#pragma unroll
      for (int mf = 0; mf < 4; ++mf)
        acc[mf][nf] = __builtin_amdgcn_mfma_f32_16x16x32_f16(aT[mf], bT, acc[mf][nf], 0, 0, 0);
    }
  }

#pragma unroll
  for (int mf = 0; mf < 4; ++mf){
    const u32 rowb = M0 + mf*16 + lk*4;
#pragma unroll
    for (int nf = 0; nf < 8; ++nf){
      const u32 col = N0 + nf*16 + lr;
#pragma unroll
      for (int r = 0; r < 4; ++r)
        xw[(unsigned long long)(rowb + r) * G4 + col] = __builtin_bit_cast(u16, (f16)acc[mf][nf][r]);
    }
  }
}

// ---------------- K2: LSTM scan v5 — 1024 thr, 4x less DS, selection butterfly ------------
// R14 skeleton (single buffer, barrier-write-barrier; PROVEN) with the DS wall removed:
// thread (j = t>>3, q = t&7) owns a 16-k slice of ALL 4 gates of col j.
// Per step: 2 ds_read_b128 (32B slice, 2-way=free), 32 dot2, selection butterfly
// (DPP177 + DPP78 keep/send, __shfl_xor(.,4)), act for gate gsel=l&3, 4 DPP bcast gather.
__global__ __attribute__((amdgpu_flat_work_group_size(1024,1024), amdgpu_waves_per_eu(4,4)))
void k_rnn(
    const u16* __restrict__ xw, const float* __restrict__ Wh,
    const float* __restrict__ h0, const float* __restrict__ c0,
    const float* __restrict__ bvec,
    const float* __restrict__ Wa1, const float* __restrict__ ba1,
    const float* __restrict__ Wa2, const float* __restrict__ ba2,
    const float* __restrict__ Wc1, const float* __restrict__ bc1,
    const float* __restrict__ Wc2, const float* __restrict__ bc2,
    const float* __restrict__ log_std, float* __restrict__ out)
{
  const int b = blockIdx.x;
  const int t = threadIdx.x;          // 0..1023
  const int j = t >> 3;               // col 0..127
  const int q = t & 7;                // 16-k slice index
  const int l = t & 63;               // lane
  const int gsel = l & 3;             // gate this lane holds after the butterfly

  __shared__ __align__(16) u16   hbuf[HID];        // h f16, SINGLE buffer (256B)
  __shared__ __align__(16) float hf[HID];          // final h fp32 (heads)
  __shared__ float hid[256];

  // ---- weights: per gate, 8 packed k-pairs of slice [16q..16q+15] for col j ----
  u32 wi[8], wf[8], wg[8], wo[8];
#pragma unroll
  for (int m = 0; m < 8; ++m){
    const u32 kb = (u32)(16*q + 2*m) * G4 + (u32)j;
    f16x2 p;
    p[0]=(f16)Wh[kb      ]; p[1]=(f16)Wh[kb+G4      ]; wi[m]=__builtin_bit_cast(u32,p);
    p[0]=(f16)Wh[kb+128  ]; p[1]=(f16)Wh[kb+G4+128  ]; wf[m]=__builtin_bit_cast(u32,p);
    p[0]=(f16)Wh[kb+256  ]; p[1]=(f16)Wh[kb+G4+256  ]; wg[m]=__builtin_bit_cast(u32,p);
    p[0]=(f16)Wh[kb+384  ]; p[1]=(f16)Wh[kb+G4+384  ]; wo[m]=__builtin_bit_cast(u32,p);
  }
#pragma unroll
  for (int m = 0; m < 8; ++m){        // pin (R7 lesson)
    asm volatile("" : "+v"(wi[m]));
    asm volatile("" : "+v"(wf[m]));
    asm volatile("" : "+v"(wg[m]));
    asm volatile("" : "+v"(wo[m]));
  }

  const float bb = bvec[j + 128*gsel];          // bias for the gate this lane activates
  const float kexp  = (gsel == 2) ? -2.88539008f : -1.44269504f;
  const float postm = (gsel == 2) ? 2.f : 1.f;
  const float posta = (gsel == 2) ? -1.f : 0.f;

  // ---- state (replicated across the 8 lanes of col j) ----
  float cs = c0[b*HID + j];
  float hv = h0[b*HID + j];
  if ((t & 7) == 0)
    hbuf[j] = __builtin_bit_cast(u16, (f16)hv);
  __syncthreads();

  const u16* xp = xw + (u32)b * G4 + (u32)(j + 128*gsel);
  float xc  = (float)__builtin_bit_cast(f16, xp[0]) + bb;
  float xn1 = (T_STEPS > 1) ? (float)__builtin_bit_cast(f16, xp[131072u]) + bb : 0.f;

  for (int s = 0; s < T_STEPS; ++s){
    // 32B h-slice: 2x ds_read_b128 (8 distinct addrs/wave -> worst 2-way = free)
    const char* hq = (const char*)hbuf + 32*q;
    u32x4 ha = *(const u32x4*)(hq);
    u32x4 hb = *(const u32x4*)(hq + 16);

    float xn2 = 0.f;
    if (s + 2 < T_STEPS)
      xn2 = (float)__builtin_bit_cast(f16, xp[(u32)(s+2) * 131072u]) + bb;

    float pi = 0.f, pf = 0.f, pg = 0.f, po = 0.f;   // 4 gate partials over 16 k
#pragma unroll
    for (int z = 0; z < 4; ++z){
      pi = dot2f(ha[z], wi[z], pi);
      pf = dot2f(ha[z], wf[z], pf);
      pg = dot2f(ha[z], wg[z], pg);
      po = dot2f(ha[z], wo[z], po);
    }
#pragma unroll
    for (int z = 0; z < 4; ++z){
      pi = dot2f(hb[z], wi[4+z], pi);
      pf = dot2f(hb[z], wf[4+z], pf);
      pg = dot2f(hb[z], wg[4+z], pg);
      po = dot2f(hb[z], wo[4+z], po);
    }

    // selection butterfly: 4 values over 8 lanes -> lane gsel holds its gate's total
    float k0 = (l & 1) ? pf : pi,  s0 = (l & 1) ? pi : pf;
    float k1 = (l & 1) ? po : pg,  s1 = (l & 1) ? pg : po;
    k0 += DPPF(s0, 177);                            // dist 1 (quad_perm, VALU)
    k1 += DPPF(s1, 177);
    float k2 = (l & 2) ? k1 : k0,  s2 = (l & 2) ? k0 : k1;
    k2 += DPPF(s2, 78);                             // dist 2 (quad_perm, VALU)
    k2 += __shfl_xor(k2, 4);                        // dist 4 (proven primitive)

    // activate gate gsel of col j
    float gval = k2 + xc;
    float av   = fmaf(postm, rcpraw(1.0f + exp2raw(kexp * gval)), posta);

    // gather all 4 gates (quad-local DPP broadcasts; both quads hold all 4)
    float ai = DPPF(av, 0);
    float af = DPPF(av, 85);
    float ag = DPPF(av, 170);
    float ao = DPPF(av, 255);

    cs = af * cs + ai * ag;
    hv = ao * tanhfast(cs);

    __syncthreads();                 // ALL reads of hbuf for step s complete
    if ((t & 7) == 0)
      hbuf[j] = __builtin_bit_cast(u16, (f16)hv);
    __syncthreads();                 // h[s+1] visible to all
    xc = xn1; xn1 = xn2;
  }

  if ((t & 7) == 0){                 // exact fp32 state out
    out[OUT_HT + b*HID + j] = hv;
    out[OUT_CT + b*HID + j] = cs;
    hf[j] = hv;
  }
  __syncthreads();

  if (t < 256){ // heads hidden, fp32: t<128 -> actor col t; else critic col t-128
    const float* W = (t < HID) ? Wa1 : Wc1;
    const int col  = t & (HID - 1);
    const f32x4* hp4 = (const f32x4*)hf;
    float a0 = 0.f, a1 = 0.f, a2 = 0.f, a3 = 0.f;
#pragma unroll
    for (int qq = 0; qq < 32; ++qq){
      f32x4 hh = hp4[qq];
      a0 = fmaf(hh.x, W[(u32)(4*qq+0)*HID + col], a0);
      a1 = fmaf(hh.y, W[(u32)(4*qq+1)*HID + col], a1);
      a2 = fmaf(hh.z, W[(u32)(4*qq+2)*HID + col], a2);
      a3 = fmaf(hh.w, W[(u32)(4*qq+3)*HID + col], a3);
    }
    float a = (a0 + a1) + (a2 + a3);
    hid[t] = (t < HID) ? tanhfast(a + ba1[col]) : tanhfast(a + bc1[col]);
  }
  __syncthreads();

  {
    const int wv = t >> 6, lane = t & 63;
    float p = 0.f;
    if (wv == 0)      p = hid[lane]     * Wa2[lane*2]   + hid[lane+64]     * Wa2[(lane+64)*2];
    else if (wv == 1) p = hid[lane]     * Wa2[lane*2+1] + hid[lane+64]     * Wa2[(lane+64)*2+1];
    else if (wv == 2) p = hid[128+lane] * Wc2[lane]     + hid[128+lane+64] * Wc2[lane+64];
    if (wv < 3){
#pragma unroll
      for (int off = 32; off > 0; off >>= 1) p += __shfl_down(p, off);
      if (lane == 0){
        if (wv == 0) out[b*2 + 0]   = p + ba2[0];
        if (wv == 1) out[b*2 + 1]   = p + ba2[1];
        if (wv == 2) out[OUT_VAL+b] = p + bc2[0];
      }
    }
    if (b == 0 && wv == 3 && lane < 2) out[OUT_STD + lane] = expf(log_std[lane]);
  }
}

extern "C" void kernel_launch(void* const* d_in, const int* in_sizes, int n_in,
                              void* d_out, int out_size, void* d_ws, size_t ws_size,
                              hipStream_t stream)
{
  (void)in_sizes; (void)n_in; (void)out_size; (void)ws_size;
  const float* x    = (const float*)d_in[0];
  const float* h0   = (const float*)d_in[1];
  const float* c0   = (const float*)d_in[2];
  const float* Wx   = (const float*)d_in[3];
  const float* Wh   = (const float*)d_in[4];
  const float* bv   = (const float*)d_in[5];
  const float* Wa1  = (const float*)d_in[6];
  const float* ba1  = (const float*)d_in[7];
  const float* Wa2  = (const float*)d_in[8];
  const float* ba2  = (const float*)d_in[9];
  const float* lstd = (const float*)d_in[10];
  const float* Wc1  = (const float*)d_in[11];
  const float* bc1  = (const float*)d_in[12];
  const float* Wc2  = (const float*)d_in[13];
  const float* bc2  = (const float*)d_in[14];
  float* out = (float*)d_out;
  char*  ws  = (char*)d_ws;

  u16* xw  = (u16*)(ws + XW_OFF);
  u16* wxt = (u16*)(ws + WXT_OFF);

  k_pack_wxt<<<dim3(512),  dim3(256),  0, stream>>>(Wx, wxt);
  k_gemm<<<dim3(2048),     dim3(256),  0, stream>>>(x, wxt, xw);
  k_rnn<<<dim3(256),       dim3(1024), 0, stream>>>(xw, Wh, h0, c0, bv,
                                                    Wa1, ba1, Wa2, ba2, Wc1, bc1, Wc2, bc2,
                                                    lstd, out);
}